// Round 16
// baseline (113.903 us; speedup 1.0000x reference)
//
#include <hip/hip_runtime.h>
#include <stdint.h>

typedef unsigned short u16;
typedef unsigned int u32;
typedef __bf16 bf16x8 __attribute__((ext_vector_type(8)));
typedef float f32x4 __attribute__((ext_vector_type(4)));
typedef unsigned short u16x8 __attribute__((ext_vector_type(8)));

#define D_MODEL 1024
#define SEQ 2048
#define NH 16
#define DK 64
#define NROWS 4096  // B*S

static __device__ __forceinline__ u16 f2bf(float f) {
  u32 u = __float_as_uint(f);
  u = (u + 0x7FFFu + ((u >> 16) & 1u)) >> 16;
  return (u16)u;
}
static __device__ __forceinline__ float bf2f(u16 h) {
  return __uint_as_float(((u32)h) << 16);
}
static __device__ __forceinline__ f32x4 mfma16(bf16x8 a, bf16x8 b, f32x4 c) {
  return __builtin_amdgcn_mfma_f32_16x16x32_bf16(a, b, c, 0, 0, 0);
}
static __device__ __forceinline__ void gload16(const void* g, void* l) {
  __builtin_amdgcn_global_load_lds(
      (const __attribute__((address_space(1))) void*)g,
      (__attribute__((address_space(3))) void*)l, 16, 0, 0);
}

// lane i gets op(x[i], x[i^32]) in ALL lanes, via v_permlane32_swap (VALU pipe).
static __device__ __forceinline__ float xor32_max(float x) {
#if __has_builtin(__builtin_amdgcn_permlane32_swap)
  u32 a = __float_as_uint(x), b = a;
  auto pr = __builtin_amdgcn_permlane32_swap(a, b, false, false);
  return fmaxf(__uint_as_float(pr[0]), __uint_as_float(pr[1]));
#else
  return fmaxf(x, __shfl_xor(x, 32));
#endif
}
static __device__ __forceinline__ float xor32_add(float x) {
#if __has_builtin(__builtin_amdgcn_permlane32_swap)
  u32 a = __float_as_uint(x), b = a;
  auto pr = __builtin_amdgcn_permlane32_swap(a, b, false, false);
  return __uint_as_float(pr[0]) + __uint_as_float(pr[1]);
#else
  return x + __shfl_xor(x, 32);
#endif
}

// ---------------- fp32 -> bf16 cast of x + weights; tail blocks build RoPE tables ----------------
__global__ __launch_bounds__(256) void k_cast(
    const float* __restrict__ x, const float* __restrict__ wq,
    const float* __restrict__ wk, const float* __restrict__ wv,
    const float* __restrict__ wo, u16* __restrict__ xb, u16* __restrict__ wqb,
    u16* __restrict__ wkb, u16* __restrict__ wvb, u16* __restrict__ wob,
    float* __restrict__ ct, float* __restrict__ st) {
  if (blockIdx.x >= 4096) {  // RoPE tables: 65536 (s,p) entries, fp64 on device
    int i = (int)(blockIdx.x - 4096) * 256 + threadIdx.x;
    int s = i >> 5, p = i & 31;
    double ang = (double)s * pow(10000.0, -(double)p / 32.0);
    ct[i] = (float)cos(ang);
    st[i] = (float)sin(ang);
    return;
  }
  size_t e = ((size_t)blockIdx.x * 256 + threadIdx.x) * 8;
  const float* s;
  u16* d;
  size_t off;
  if (e < (size_t)NROWS * D_MODEL) {
    s = x; d = xb; off = e;
  } else {
    size_t r = e - (size_t)NROWS * D_MODEL;
    unsigned wi = (unsigned)(r >> 20);
    off = r & 1048575u;
    s = wi == 0 ? wq : wi == 1 ? wk : wi == 2 ? wv : wo;
    d = wi == 0 ? wqb : wi == 1 ? wkb : wi == 2 ? wvb : wob;
  }
  float4 a = *(const float4*)(s + off);
  float4 b = *(const float4*)(s + off + 4);
  u16x8 o;
  o[0] = f2bf(a.x); o[1] = f2bf(a.y); o[2] = f2bf(a.z); o[3] = f2bf(a.w);
  o[4] = f2bf(b.x); o[5] = f2bf(b.y); o[6] = f2bf(b.z); o[7] = f2bf(b.w);
  *(u16x8*)(d + off) = o;
}

// ---------------- fused QKV bf16 B^T GEMM: qkv[4096][3072] ----------------
// m97 structure, BK=64 (32 MFMA per barrier-pair) + T2 XOR-swizzled LDS:
// linear DMA dest + inverse-swizzled global source col + swizzled ds_read.
__global__ __launch_bounds__(256, 1) void k_gemm3(
    const u16* __restrict__ A, const u16* __restrict__ B0,
    const u16* __restrict__ B1, const u16* __restrict__ B2,
    u16* __restrict__ Cb) {
  constexpr int K = 1024;
  const int mb = blockIdx.x, nb = blockIdx.y;
  const int tid = threadIdx.x;
  const int lane = tid & 63, w = tid >> 6;
  const int lq = lane & 15, lg = lane >> 4;
  const int wm = w >> 1, wn = w & 1;
  __shared__ __align__(16) u16 As[128 * 64];  // 16 KB, row = 128 B
  __shared__ __align__(16) u16 Bs[128 * 64];  // 16 KB

  const int sel = nb >> 3;
  const u16* Bp = sel == 0 ? B0 : (sel == 1 ? B1 : B2);
  const int nloc = (nb & 7) * 128;
  const char* Ab = (const char*)A + (size_t)mb * 128 * 2048;
  const char* Bb = (const char*)Bp + (size_t)nloc * 2048;

  f32x4 zero4 = {0.f, 0.f, 0.f, 0.f};
  f32x4 acc[4][4];
#pragma unroll
  for (int i = 0; i < 4; ++i)
#pragma unroll
    for (int j = 0; j < 4; ++j) acc[i][j] = zero4;

  for (int k0 = 0; k0 < K; k0 += 64) {
#pragma unroll
    for (int c = 0; c < 4; ++c) {
      int ch = c * 256 + tid;                         // 0..1023 16B chunks
      int srow = ch >> 3;                             // 0..127
      int scb = ((ch & 7) * 16) ^ ((srow & 7) << 4);  // inverse-swizzled source
      const char* ga = Ab + (size_t)srow * 2048 + k0 * 2 + scb;
      const char* gb = Bb + (size_t)srow * 2048 + k0 * 2 + scb;
      gload16(ga, (char*)As + ch * 16);               // linear dest
      gload16(gb, (char*)Bs + ch * 16);
    }
    __syncthreads();  // drains DMA + aligns waves
#pragma unroll
    for (int ks = 0; ks < 2; ++ks) {
      bf16x8 af[4], bfr[4];
#pragma unroll
      for (int i = 0; i < 4; ++i) {
        int ra = wm * 64 + i * 16 + lq;
        int rb = wn * 64 + i * 16 + lq;
        af[i] = *(const bf16x8*)((const char*)As +
                                 ra * 128 + ((ks * 64 + lg * 16) ^ ((ra & 7) << 4)));
        bfr[i] = *(const bf16x8*)((const char*)Bs +
                                  rb * 128 + ((ks * 64 + lg * 16) ^ ((rb & 7) << 4)));
      }
#pragma unroll
      for (int i = 0; i < 4; ++i)
#pragma unroll
        for (int j = 0; j < 4; ++j) acc[i][j] = mfma16(af[i], bfr[j], acc[i][j]);
    }
    __syncthreads();  // reads done before next-tile DMA overwrites
  }

#pragma unroll
  for (int i = 0; i < 4; ++i) {
#pragma unroll
    for (int r = 0; r < 4; ++r) {
      size_t rowg = (size_t)(mb * 128 + wm * 64 + i * 16 + lg * 4 + r);
#pragma unroll
      for (int j = 0; j < 4; ++j) {
        int colg = nb * 128 + wn * 64 + j * 16 + lq;
        Cb[rowg * 3072 + colg] = f2bf(acc[i][j][r]);
      }
    }
  }
}

// ---------------- RoPE apply + reshape to head-major [BH][S][64] ----------------
// Q additionally pre-scaled by 0.125*log2(e) (exp2-domain softmax downstream).
__global__ __launch_bounds__(256) void k_rope(const u16* __restrict__ qkv,
                                              const float* __restrict__ ct,
                                              const float* __restrict__ st,
                                              u16* __restrict__ qh, u16* __restrict__ kh) {
  int gi = blockIdx.x * 256 + threadIdx.x;  // 524288
  int row = gi >> 7;
  int col = (gi & 127) << 3;
  int h = col >> 6, d0 = col & 63;
  int b = row >> 11, s = row & 2047;
  const int srcoff = blockIdx.y ? 1024 : 0;
  const float qs = blockIdx.y ? 1.0f : 0.18033688011112042f;
  u16x8 v = *(const u16x8*)(qkv + (size_t)row * 3072 + srcoff + col);
  const float* cp = ct + s * 32 + (d0 >> 1);
  const float* sp = st + s * 32 + (d0 >> 1);
  u16x8 o;
#pragma unroll
  for (int i = 0; i < 4; ++i) {
    float ev = bf2f(v[2 * i]), od = bf2f(v[2 * i + 1]);
    float c = cp[i], sn = sp[i];
    o[2 * i] = f2bf((ev * c - od * sn) * qs);
    o[2 * i + 1] = f2bf((ev * sn + od * c) * qs);
  }
  u16* dst = blockIdx.y ? kh : qh;
  *(u16x8*)(dst + (((size_t)(b * 16 + h) * SEQ + s) << 6) + d0) = o;
}

// ---------------- V transpose: qkv V cols -> Vt [BH][64][S] ----------------
__global__ __launch_bounds__(256) void k_vtrans(const u16* __restrict__ qkv,
                                                u16* __restrict__ vt) {
  __shared__ __align__(16) u16 t[64][72];
  int sb = blockIdx.x, bh = blockIdx.y;
  int b = bh >> 4, h = bh & 15;
  int tid = threadIdx.x;
#pragma unroll
  for (int c = 0; c < 2; ++c) {
    int o = tid * 8 + c * 2048;
    int r = o >> 6, d = o & 63;
    u16x8 v = *(const u16x8*)(qkv + (size_t)(b * SEQ + sb * 64 + r) * 3072 + 2048 + h * 64 + d);
    *(u16x8*)&t[r][d] = v;
  }
  __syncthreads();
#pragma unroll
  for (int c = 0; c < 2; ++c) {
    int o = tid * 8 + c * 2048;
    int d = o >> 6, si = o & 63;
    u16x8 v;
#pragma unroll
    for (int j = 0; j < 8; ++j) v[j] = t[si + j][d];
    *(u16x8*)(vt + ((size_t)bh * 64 + d) * SEQ + sb * 64 + si) = v;
  }
}

// ---------------- out-projection GEMM: BM=128 BN=64, BK=64, swizzled ----------------
__global__ __launch_bounds__(256, 2) void k_gemmo(const u16* __restrict__ A,
                                                  const u16* __restrict__ B0,
                                                  float* __restrict__ Cf) {
  constexpr int K = 1024;
  const int mb = blockIdx.x, nb = blockIdx.y;
  const int tid = threadIdx.x;
  const int lane = tid & 63, w = tid >> 6;
  const int lq = lane & 15, lg = lane >> 4;
  const int wm = w >> 1, wn = w & 1;
  __shared__ __align__(16) u16 As[128 * 64];  // 16 KB
  __shared__ __align__(16) u16 Bs[64 * 64];   // 8 KB

  const char* Ab = (const char*)A + (size_t)mb * 128 * 2048;
  const char* Bb = (const char*)B0 + (size_t)(nb * 64) * 2048;

  f32x4 zero4 = {0.f, 0.f, 0.f, 0.f};
  f32x4 acc[4][2];
#pragma unroll
  for (int i = 0; i < 4; ++i) {
    acc[i][0] = zero4; acc[i][1] = zero4;
  }

  for (int k0 = 0; k0 < K; k0 += 64) {
#pragma unroll
    for (int c = 0; c < 4; ++c) {
      int ch = c * 256 + tid;
      int srow = ch >> 3;
      int scb = ((ch & 7) * 16) ^ ((srow & 7) << 4);
      gload16(Ab + (size_t)srow * 2048 + k0 * 2 + scb, (char*)As + ch * 16);
      if (c < 2)
        gload16(Bb + (size_t)srow * 2048 + k0 * 2 + scb, (char*)Bs + ch * 16);
    }
    __syncthreads();
#pragma unroll
    for (int ks = 0; ks < 2; ++ks) {
      bf16x8 af[4], bfr[2];
#pragma unroll
      for (int i = 0; i < 4; ++i) {
        int ra = wm * 64 + i * 16 + lq;
        af[i] = *(const bf16x8*)((const char*)As +
                                 ra * 128 + ((ks * 64 + lg * 16) ^ ((ra & 7) << 4)));
      }
#pragma unroll
      for (int j = 0; j < 2; ++j) {
        int rb = wn * 32 + j * 16 + lq;
        bfr[j] = *(const bf16x8*)((const char*)Bs +
                                  rb * 128 + ((ks * 64 + lg * 16) ^ ((rb & 7) << 4)));
      }
#pragma unroll
      for (int i = 0; i < 4; ++i)
#pragma unroll
        for (int j = 0; j < 2; ++j) acc[i][j] = mfma16(af[i], bfr[j], acc[i][j]);
    }
    __syncthreads();
  }

#pragma unroll
  for (int i = 0; i < 4; ++i) {
#pragma unroll
    for (int r = 0; r < 4; ++r) {
      size_t rowg = (size_t)(mb * 128 + wm * 64 + i * 16 + lg * 4 + r);
#pragma unroll
      for (int j = 0; j < 2; ++j) {
        int colg = nb * 64 + wn * 32 + j * 16 + lq;
        Cf[rowg * 1024 + colg] = acc[i][j][r];
      }
    }
  }
}

// ---------------- one kv-subtile (64 keys) for one 16-row strip ----------------
static __device__ __forceinline__ void attn_tile(
    const u16* Kl, const u16* Vl, u16* Plw, int k0, int qrow, int lq, int lg,
    bf16x8 qf0, bf16x8 qf1, float& m_run, float& l_run, f32x4* accO, bool masked) {
  f32x4 zero4 = {0.f, 0.f, 0.f, 0.f};
  f32x4 sa[4];
  sa[0] = zero4; sa[1] = zero4; sa[2] = zero4; sa[3] = zero4;
  __builtin_amdgcn_s_setprio(1);
#pragma unroll
  for (int kt = 0; kt < 4; ++kt) {
    int krow = kt * 16 + lq;
    int base = krow * 128 + lg * 16;
    int swz = (krow & 7) << 4;
    bf16x8 kf0 = *(const bf16x8*)((const char*)Kl + (base ^ swz));
    bf16x8 kf1 = *(const bf16x8*)((const char*)Kl + ((base + 64) ^ swz));
    sa[kt] = mfma16(kf0, qf0, sa[kt]);
    sa[kt] = mfma16(kf1, qf1, sa[kt]);
  }
  __builtin_amdgcn_s_setprio(0);

  float p[16];
#pragma unroll
  for (int kt = 0; kt < 4; ++kt)
#pragma unroll
    for (int r = 0; r < 4; ++r) p[kt * 4 + r] = sa[kt][r];
  if (masked) {
#pragma unroll
    for (int kt = 0; kt < 4; ++kt)
#pragma unroll
      for (int r = 0; r < 4; ++r) {
        int key = k0 + kt * 16 + lg * 4 + r;
        if (key > qrow) p[kt * 4 + r] = -1e30f;
      }
  }
  // depth-4 pairwise max tree
  float x0 = fmaxf(p[0], p[1]), x1 = fmaxf(p[2], p[3]);
  float x2 = fmaxf(p[4], p[5]), x3 = fmaxf(p[6], p[7]);
  float x4 = fmaxf(p[8], p[9]), x5 = fmaxf(p[10], p[11]);
  float x6 = fmaxf(p[12], p[13]), x7 = fmaxf(p[14], p[15]);
  x0 = fmaxf(x0, x1); x2 = fmaxf(x2, x3); x4 = fmaxf(x4, x5); x6 = fmaxf(x6, x7);
  x0 = fmaxf(x0, x2); x4 = fmaxf(x4, x6);
  float pm = fmaxf(x0, x4);
  pm = fmaxf(pm, __shfl_xor(pm, 16));
  pm = xor32_max(pm);
  const bool resc = __any(pm > m_run + 8.0f);  // defer-max, wave-uniform
  float mnew = resc ? fmaxf(m_run, pm) : m_run;
#pragma unroll
  for (int i = 0; i < 16; ++i) p[i] = __builtin_amdgcn_exp2f(p[i] - mnew);
  // depth-4 pairwise sum tree
  float s0 = p[0] + p[1], s1 = p[2] + p[3], s2 = p[4] + p[5], s3 = p[6] + p[7];
  float s4 = p[8] + p[9], s5 = p[10] + p[11], s6 = p[12] + p[13], s7 = p[14] + p[15];
  s0 += s1; s2 += s3; s4 += s5; s6 += s7;
  s0 += s2; s4 += s6;
  float rs = s0 + s4;
  rs += __shfl_xor(rs, 16);
  rs = xor32_add(rs);
  if (resc) {
    float alpha = __builtin_amdgcn_exp2f(m_run - mnew);
    l_run = l_run * alpha + rs;
    m_run = mnew;
#pragma unroll
    for (int r = 0; r < 4; ++r) {
      float ar = __shfl(alpha, lg * 4 + r);
#pragma unroll
      for (int dt = 0; dt < 4; ++dt) accO[dt][r] *= ar;
    }
  } else {
    l_run += rs;
  }

  // P -> per-wave LDS (bf16 via v_cvt_pk, swizzled [q][k])
  {
    int swz = (lq & 7) << 4;
#pragma unroll
    for (int kt = 0; kt < 4; ++kt) {
      u32 w0, w1;
      asm("v_cvt_pk_bf16_f32 %0, %1, %2"
          : "=v"(w0) : "v"(p[kt * 4 + 0]), "v"(p[kt * 4 + 1]));
      asm("v_cvt_pk_bf16_f32 %0, %1, %2"
          : "=v"(w1) : "v"(p[kt * 4 + 2]), "v"(p[kt * 4 + 3]));
      int a0 = (lq * 128 + (kt * 16 + lg * 4) * 2) ^ swz;
      int a1 = (lq * 128 + (kt * 16 + lg * 4 + 2) * 2) ^ swz;
      *(u32*)((char*)Plw + a0) = w0;
      *(u32*)((char*)Plw + a1) = w1;
    }
  }
  // PV: O[q][d] += P[q][k] * V[k][d]
  {
    int swz = (lq & 7) << 4;
    bf16x8 pa0 = *(const bf16x8*)((const char*)Plw + ((lq * 128 + lg * 16) ^ swz));
    bf16x8 pa1 = *(const bf16x8*)((const char*)Plw + ((lq * 128 + 64 + lg * 16) ^ swz));
    __builtin_amdgcn_s_setprio(1);
#pragma unroll
    for (int dt = 0; dt < 4; ++dt) {
      int vrow = dt * 16 + lq;
      int vb = vrow * 128 + lg * 16;
      int vs = (vrow & 7) << 4;
      bf16x8 v0 = *(const bf16x8*)((const char*)Vl + (vb ^ vs));
      bf16x8 v1 = *(const bf16x8*)((const char*)Vl + ((vb + 64) ^ vs));
      accO[dt] = mfma16(pa0, v0, accO[dt]);
      accO[dt] = mfma16(pa1, v1, accO[dt]);
    }
    __builtin_amdgcn_s_setprio(0);
  }
}

// ---------------- causal flash attention ----------------
// grid (16 pairs, 32 bh) = 512 blocks of 4 waves. KVBLK=64 double-buffered
// (Kd/Vd 2x8KB each + Pl 8KB = 40KB LDS) -> 4 blocks/CU = 4 waves/SIMD (2x
// the TLP of the 72KB KVBLK=128 variant; barrier count ~2x but 4 independent
// barrier domains per CU overlap each other's drains). Block handles 64-row
// q-blocks qb1=x and qb2=31-x; per-wave work = 33 subtiles, uniform.
__global__ __launch_bounds__(256, 4) void k_attn(const u16* __restrict__ qh,
                                                 const u16* __restrict__ kh,
                                                 const u16* __restrict__ vt,
                                                 u16* __restrict__ ao) {
  const int qb1 = (int)blockIdx.x;   // 0..15
  const int qb2 = 31 - qb1;          // 16..31
  const int bh = blockIdx.y;
  const int tid = threadIdx.x;
  const int w = tid >> 6;  // 0..3
  const int lane = tid & 63;
  const int lq = lane & 15;
  const int lg = lane >> 4;

  __shared__ __align__(16) u16 Kd[2][64 * 64];  // 16 KB
  __shared__ __align__(16) u16 Vd[2][64 * 64];  // 16 KB
  __shared__ __align__(16) u16 Pl[4][16 * 64];  // 8 KB

  const int qtop1 = qb1 * 64 + w * 16;
  const int qtop2 = qb2 * 64 + w * 16;
  const int qrow1 = qtop1 + lq;
  const int qrow2 = qtop2 + lq;

  const u16* qp1 = qh + ((size_t)bh * SEQ + qrow1) * DK + lg * 8;
  const u16* qp2 = qh + ((size_t)bh * SEQ + qrow2) * DK + lg * 8;
  bf16x8 qa0 = *(const bf16x8*)qp1;
  bf16x8 qa1 = *(const bf16x8*)(qp1 + 32);
  bf16x8 qc0 = *(const bf16x8*)qp2;
  bf16x8 qc1 = *(const bf16x8*)(qp2 + 32);

  f32x4 zero4 = {0.f, 0.f, 0.f, 0.f};
  f32x4 acc1[4], acc2[4];
#pragma unroll
  for (int dt = 0; dt < 4; ++dt) { acc1[dt] = zero4; acc2[dt] = zero4; }
  float m1 = -1e30f, l1 = 0.f, m2 = -1e30f, l2 = 0.f;

  const int nt1 = qb1 + 1;   // strip-1 subtile participation
  const int NT = qb2 + 1;    // strip-2 participation == block subtile count

  const char* kb_ = (const char*)kh + (size_t)bh * SEQ * 128;  // 128 B/row
  const char* vb_ = (const char*)vt + (size_t)bh * DK * 4096;  // 4096 B/row

  // prologue: stage subtile 0 into buf 0 (2 chunks of 16B per thread each)
#pragma unroll
  for (int pass = 0; pass < 2; ++pass) {
    int chunk = pass * 256 + tid;          // 0..511
    int srow = chunk >> 3;                 // 0..63
    int colb = ((chunk & 7) * 16) ^ ((srow & 7) << 4);
    gload16(kb_ + (size_t)srow * 128 + colb, (char*)Kd[0] + chunk * 16);
    gload16(vb_ + (size_t)srow * 4096 + colb, (char*)Vd[0] + chunk * 16);
  }
  __syncthreads();

  for (int t = 0; t < NT; ++t) {
    const int cur = t & 1;
    if (t + 1 < NT) {  // stage next subtile; lands during compute
      int kb0 = (t + 1) * 64;
#pragma unroll
      for (int pass = 0; pass < 2; ++pass) {
        int chunk = pass * 256 + tid;
        int srow = chunk >> 3;
        int colb = ((chunk & 7) * 16) ^ ((srow & 7) << 4);
        gload16(kb_ + (size_t)(kb0 + srow) * 128 + colb,
                (char*)Kd[cur ^ 1] + chunk * 16);
        gload16(vb_ + (size_t)srow * 4096 + kb0 * 2 + colb,
                (char*)Vd[cur ^ 1] + chunk * 16);
      }
    }
    const int k0 = t * 64;
    if (t < nt1)
      attn_tile(Kd[cur], Vd[cur], Pl[w], k0, qrow1, lq, lg, qa0, qa1,
                m1, l1, acc1, t == nt1 - 1);
    attn_tile(Kd[cur], Vd[cur], Pl[w], k0, qrow2, lq, lg, qc0, qc1,
              m2, l2, acc2, t == NT - 1);
    __syncthreads();  // one barrier per 64 keys (drains next-subtile DMA)
  }

  const int b = bh >> 4, h = bh & 15;
#pragma unroll
  for (int r = 0; r < 4; ++r) {
    float lr = __shfl(l1, lg * 4 + r);
    float inv = 1.f / (lr + 1e-9f);
    int qq = qtop1 + lg * 4 + r;
    u16* orow = ao + ((size_t)b * SEQ + qq) * D_MODEL + h * DK;
#pragma unroll
    for (int dt = 0; dt < 4; ++dt) orow[dt * 16 + lq] = f2bf(acc1[dt][r] * inv);
  }
#pragma unroll
  for (int r = 0; r < 4; ++r) {
    float lr = __shfl(l2, lg * 4 + r);
    float inv = 1.f / (lr + 1e-9f);
    int qq = qtop2 + lg * 4 + r;
    u16* orow = ao + ((size_t)b * SEQ + qq) * D_MODEL + h * DK;
#pragma unroll
    for (int dt = 0; dt < 4; ++dt) orow[dt * 16 + lq] = f2bf(acc2[dt][r] * inv);
  }
}

extern "C" void kernel_launch(void* const* d_in, const int* in_sizes, int n_in,
                              void* d_out, int out_size, void* d_ws, size_t ws_size,
                              hipStream_t stream) {
  const float* x = (const float*)d_in[0];
  const float* wq = (const float*)d_in[1];
  const float* wk = (const float*)d_in[2];
  const float* wv = (const float*)d_in[3];
  const float* wo = (const float*)d_in[4];
  float* out = (float*)d_out;
  char* ws = (char*)d_ws;

  u16* xb   = (u16*)(ws + 0);             // 8 MB
  u16* wqb  = (u16*)(ws + 8388608);       // 2 MB each
  u16* wkb  = (u16*)(ws + 10485760);
  u16* wvb  = (u16*)(ws + 12582912);
  u16* wob  = (u16*)(ws + 14680064);
  u16* qkv  = (u16*)(ws + 16777216);      // 24 MB [4096][3072]
  u16* qhb  = (u16*)(ws + 41943040);      // 8 MB [32][2048][64]
  u16* khb  = (u16*)(ws + 50331648);      // 8 MB
  u16* vtb  = (u16*)(ws + 58720256);      // 8 MB [32][64][2048]
  u16* aob  = (u16*)(ws + 67108864);      // 8 MB [4096][1024]
  float* ct = (float*)(ws + 75497472);    // 256 KB
  float* st = (float*)(ws + 75759616);    // 256 KB

  k_cast<<<4352, 256, 0, stream>>>(x, wq, wk, wv, wo, xb, wqb, wkb, wvb, wob, ct, st);
  k_gemm3<<<dim3(32, 24), 256, 0, stream>>>(xb, wqb, wkb, wvb, qkv);
  k_rope<<<dim3(2048, 2), 256, 0, stream>>>(qkv, ct, st, qhb, khb);
  k_vtrans<<<dim3(32, 32), 256, 0, stream>>>(qkv, vtb);
  k_attn<<<dim3(16, 32), 256, 0, stream>>>(qhb, khb, vtb, aob);
  k_gemmo<<<dim3(32, 16), 256, 0, stream>>>(aob, wob, out);
}

// Round 17
// 113.163 us; speedup vs baseline: 1.0065x; 1.0065x over previous
//
#include <hip/hip_runtime.h>
#include <stdint.h>

typedef unsigned short u16;
typedef unsigned int u32;
typedef __bf16 bf16x8 __attribute__((ext_vector_type(8)));
typedef float f32x4 __attribute__((ext_vector_type(4)));
typedef unsigned short u16x8 __attribute__((ext_vector_type(8)));

#define D_MODEL 1024
#define SEQ 2048
#define NH 16
#define DK 64
#define NROWS 4096  // B*S

static __device__ __forceinline__ u16 f2bf(float f) {
  u32 u = __float_as_uint(f);
  u = (u + 0x7FFFu + ((u >> 16) & 1u)) >> 16;
  return (u16)u;
}
static __device__ __forceinline__ float bf2f(u16 h) {
  return __uint_as_float(((u32)h) << 16);
}
static __device__ __forceinline__ f32x4 mfma16(bf16x8 a, bf16x8 b, f32x4 c) {
  return __builtin_amdgcn_mfma_f32_16x16x32_bf16(a, b, c, 0, 0, 0);
}
static __device__ __forceinline__ void gload16(const void* g, void* l) {
  __builtin_amdgcn_global_load_lds(
      (const __attribute__((address_space(1))) void*)g,
      (__attribute__((address_space(3))) void*)l, 16, 0, 0);
}

// lane i gets op(x[i], x[i^32]) in ALL lanes, via v_permlane32_swap (VALU pipe).
static __device__ __forceinline__ float xor32_max(float x) {
#if __has_builtin(__builtin_amdgcn_permlane32_swap)
  u32 a = __float_as_uint(x), b = a;
  auto pr = __builtin_amdgcn_permlane32_swap(a, b, false, false);
  return fmaxf(__uint_as_float(pr[0]), __uint_as_float(pr[1]));
#else
  return fmaxf(x, __shfl_xor(x, 32));
#endif
}
static __device__ __forceinline__ float xor32_add(float x) {
#if __has_builtin(__builtin_amdgcn_permlane32_swap)
  u32 a = __float_as_uint(x), b = a;
  auto pr = __builtin_amdgcn_permlane32_swap(a, b, false, false);
  return __uint_as_float(pr[0]) + __uint_as_float(pr[1]);
#else
  return x + __shfl_xor(x, 32);
#endif
}

// ---------------- fp32 -> bf16 cast of x + weights; tail blocks build RoPE tables ----------------
__global__ __launch_bounds__(256) void k_cast(
    const float* __restrict__ x, const float* __restrict__ wq,
    const float* __restrict__ wk, const float* __restrict__ wv,
    const float* __restrict__ wo, u16* __restrict__ xb, u16* __restrict__ wqb,
    u16* __restrict__ wkb, u16* __restrict__ wvb, u16* __restrict__ wob,
    float* __restrict__ ct, float* __restrict__ st) {
  if (blockIdx.x >= 4096) {  // RoPE tables: 65536 (s,p) entries, fp64 on device
    int i = (int)(blockIdx.x - 4096) * 256 + threadIdx.x;
    int s = i >> 5, p = i & 31;
    double ang = (double)s * pow(10000.0, -(double)p / 32.0);
    ct[i] = (float)cos(ang);
    st[i] = (float)sin(ang);
    return;
  }
  size_t e = ((size_t)blockIdx.x * 256 + threadIdx.x) * 8;
  const float* s;
  u16* d;
  size_t off;
  if (e < (size_t)NROWS * D_MODEL) {
    s = x; d = xb; off = e;
  } else {
    size_t r = e - (size_t)NROWS * D_MODEL;
    unsigned wi = (unsigned)(r >> 20);
    off = r & 1048575u;
    s = wi == 0 ? wq : wi == 1 ? wk : wi == 2 ? wv : wo;
    d = wi == 0 ? wqb : wi == 1 ? wkb : wi == 2 ? wvb : wob;
  }
  float4 a = *(const float4*)(s + off);
  float4 b = *(const float4*)(s + off + 4);
  u16x8 o;
  o[0] = f2bf(a.x); o[1] = f2bf(a.y); o[2] = f2bf(a.z); o[3] = f2bf(a.w);
  o[4] = f2bf(b.x); o[5] = f2bf(b.y); o[6] = f2bf(b.z); o[7] = f2bf(b.w);
  *(u16x8*)(d + off) = o;
}

// ---------------- fused QKV bf16 B^T GEMM: qkv[4096][3072] ----------------
// m97 structure, BK=64 (32 MFMA per barrier-pair) + T2 XOR-swizzled LDS:
// linear DMA dest + inverse-swizzled global source col + swizzled ds_read.
__global__ __launch_bounds__(256, 1) void k_gemm3(
    const u16* __restrict__ A, const u16* __restrict__ B0,
    const u16* __restrict__ B1, const u16* __restrict__ B2,
    u16* __restrict__ Cb) {
  constexpr int K = 1024;
  const int mb = blockIdx.x, nb = blockIdx.y;
  const int tid = threadIdx.x;
  const int lane = tid & 63, w = tid >> 6;
  const int lq = lane & 15, lg = lane >> 4;
  const int wm = w >> 1, wn = w & 1;
  __shared__ __align__(16) u16 As[128 * 64];  // 16 KB, row = 128 B
  __shared__ __align__(16) u16 Bs[128 * 64];  // 16 KB

  const int sel = nb >> 3;
  const u16* Bp = sel == 0 ? B0 : (sel == 1 ? B1 : B2);
  const int nloc = (nb & 7) * 128;
  const char* Ab = (const char*)A + (size_t)mb * 128 * 2048;
  const char* Bb = (const char*)Bp + (size_t)nloc * 2048;

  f32x4 zero4 = {0.f, 0.f, 0.f, 0.f};
  f32x4 acc[4][4];
#pragma unroll
  for (int i = 0; i < 4; ++i)
#pragma unroll
    for (int j = 0; j < 4; ++j) acc[i][j] = zero4;

  for (int k0 = 0; k0 < K; k0 += 64) {
#pragma unroll
    for (int c = 0; c < 4; ++c) {
      int ch = c * 256 + tid;                         // 0..1023 16B chunks
      int srow = ch >> 3;                             // 0..127
      int scb = ((ch & 7) * 16) ^ ((srow & 7) << 4);  // inverse-swizzled source
      const char* ga = Ab + (size_t)srow * 2048 + k0 * 2 + scb;
      const char* gb = Bb + (size_t)srow * 2048 + k0 * 2 + scb;
      gload16(ga, (char*)As + ch * 16);               // linear dest
      gload16(gb, (char*)Bs + ch * 16);
    }
    __syncthreads();  // drains DMA + aligns waves
#pragma unroll
    for (int ks = 0; ks < 2; ++ks) {
      bf16x8 af[4], bfr[4];
#pragma unroll
      for (int i = 0; i < 4; ++i) {
        int ra = wm * 64 + i * 16 + lq;
        int rb = wn * 64 + i * 16 + lq;
        af[i] = *(const bf16x8*)((const char*)As +
                                 ra * 128 + ((ks * 64 + lg * 16) ^ ((ra & 7) << 4)));
        bfr[i] = *(const bf16x8*)((const char*)Bs +
                                  rb * 128 + ((ks * 64 + lg * 16) ^ ((rb & 7) << 4)));
      }
#pragma unroll
      for (int i = 0; i < 4; ++i)
#pragma unroll
        for (int j = 0; j < 4; ++j) acc[i][j] = mfma16(af[i], bfr[j], acc[i][j]);
    }
    __syncthreads();  // reads done before next-tile DMA overwrites
  }

#pragma unroll
  for (int i = 0; i < 4; ++i) {
#pragma unroll
    for (int r = 0; r < 4; ++r) {
      size_t rowg = (size_t)(mb * 128 + wm * 64 + i * 16 + lg * 4 + r);
#pragma unroll
      for (int j = 0; j < 4; ++j) {
        int colg = nb * 128 + wn * 64 + j * 16 + lq;
        Cb[rowg * 3072 + colg] = f2bf(acc[i][j][r]);
      }
    }
  }
}

// ---------------- RoPE apply + reshape to head-major [BH][S][64] ----------------
// Q additionally pre-scaled by 0.125*log2(e) (exp2-domain softmax downstream).
__global__ __launch_bounds__(256) void k_rope(const u16* __restrict__ qkv,
                                              const float* __restrict__ ct,
                                              const float* __restrict__ st,
                                              u16* __restrict__ qh, u16* __restrict__ kh) {
  int gi = blockIdx.x * 256 + threadIdx.x;  // 524288
  int row = gi >> 7;
  int col = (gi & 127) << 3;
  int h = col >> 6, d0 = col & 63;
  int b = row >> 11, s = row & 2047;
  const int srcoff = blockIdx.y ? 1024 : 0;
  const float qs = blockIdx.y ? 1.0f : 0.18033688011112042f;
  u16x8 v = *(const u16x8*)(qkv + (size_t)row * 3072 + srcoff + col);
  const float* cp = ct + s * 32 + (d0 >> 1);
  const float* sp = st + s * 32 + (d0 >> 1);
  u16x8 o;
#pragma unroll
  for (int i = 0; i < 4; ++i) {
    float ev = bf2f(v[2 * i]), od = bf2f(v[2 * i + 1]);
    float c = cp[i], sn = sp[i];
    o[2 * i] = f2bf((ev * c - od * sn) * qs);
    o[2 * i + 1] = f2bf((ev * sn + od * c) * qs);
  }
  u16* dst = blockIdx.y ? kh : qh;
  *(u16x8*)(dst + (((size_t)(b * 16 + h) * SEQ + s) << 6) + d0) = o;
}

// ---------------- V transpose: qkv V cols -> Vt [BH][64][S] ----------------
__global__ __launch_bounds__(256) void k_vtrans(const u16* __restrict__ qkv,
                                                u16* __restrict__ vt) {
  __shared__ __align__(16) u16 t[64][72];
  int sb = blockIdx.x, bh = blockIdx.y;
  int b = bh >> 4, h = bh & 15;
  int tid = threadIdx.x;
#pragma unroll
  for (int c = 0; c < 2; ++c) {
    int o = tid * 8 + c * 2048;
    int r = o >> 6, d = o & 63;
    u16x8 v = *(const u16x8*)(qkv + (size_t)(b * SEQ + sb * 64 + r) * 3072 + 2048 + h * 64 + d);
    *(u16x8*)&t[r][d] = v;
  }
  __syncthreads();
#pragma unroll
  for (int c = 0; c < 2; ++c) {
    int o = tid * 8 + c * 2048;
    int d = o >> 6, si = o & 63;
    u16x8 v;
#pragma unroll
    for (int j = 0; j < 8; ++j) v[j] = t[si + j][d];
    *(u16x8*)(vt + ((size_t)bh * 64 + d) * SEQ + sb * 64 + si) = v;
  }
}

// ---------------- out-projection GEMM: BM=128 BN=64, BK=64, swizzled ----------------
__global__ __launch_bounds__(256, 2) void k_gemmo(const u16* __restrict__ A,
                                                  const u16* __restrict__ B0,
                                                  float* __restrict__ Cf) {
  constexpr int K = 1024;
  const int mb = blockIdx.x, nb = blockIdx.y;
  const int tid = threadIdx.x;
  const int lane = tid & 63, w = tid >> 6;
  const int lq = lane & 15, lg = lane >> 4;
  const int wm = w >> 1, wn = w & 1;
  __shared__ __align__(16) u16 As[128 * 64];  // 16 KB
  __shared__ __align__(16) u16 Bs[64 * 64];   // 8 KB

  const char* Ab = (const char*)A + (size_t)mb * 128 * 2048;
  const char* Bb = (const char*)B0 + (size_t)(nb * 64) * 2048;

  f32x4 zero4 = {0.f, 0.f, 0.f, 0.f};
  f32x4 acc[4][2];
#pragma unroll
  for (int i = 0; i < 4; ++i) {
    acc[i][0] = zero4; acc[i][1] = zero4;
  }

  for (int k0 = 0; k0 < K; k0 += 64) {
#pragma unroll
    for (int c = 0; c < 4; ++c) {
      int ch = c * 256 + tid;
      int srow = ch >> 3;
      int scb = ((ch & 7) * 16) ^ ((srow & 7) << 4);
      gload16(Ab + (size_t)srow * 2048 + k0 * 2 + scb, (char*)As + ch * 16);
      if (c < 2)
        gload16(Bb + (size_t)srow * 2048 + k0 * 2 + scb, (char*)Bs + ch * 16);
    }
    __syncthreads();
#pragma unroll
    for (int ks = 0; ks < 2; ++ks) {
      bf16x8 af[4], bfr[2];
#pragma unroll
      for (int i = 0; i < 4; ++i) {
        int ra = wm * 64 + i * 16 + lq;
        af[i] = *(const bf16x8*)((const char*)As +
                                 ra * 128 + ((ks * 64 + lg * 16) ^ ((ra & 7) << 4)));
      }
#pragma unroll
      for (int j = 0; j < 2; ++j) {
        int rb = wn * 32 + j * 16 + lq;
        bfr[j] = *(const bf16x8*)((const char*)Bs +
                                  rb * 128 + ((ks * 64 + lg * 16) ^ ((rb & 7) << 4)));
      }
#pragma unroll
      for (int i = 0; i < 4; ++i)
#pragma unroll
        for (int j = 0; j < 2; ++j) acc[i][j] = mfma16(af[i], bfr[j], acc[i][j]);
    }
    __syncthreads();
  }

#pragma unroll
  for (int i = 0; i < 4; ++i) {
#pragma unroll
    for (int r = 0; r < 4; ++r) {
      size_t rowg = (size_t)(mb * 128 + wm * 64 + i * 16 + lg * 4 + r);
#pragma unroll
      for (int j = 0; j < 2; ++j) {
        int colg = nb * 64 + wn * 32 + j * 16 + lq;
        Cf[rowg * 1024 + colg] = acc[i][j][r];
      }
    }
  }
}

// ---------------- one kv-subtile (64 keys) for one 16-row strip ----------------
static __device__ __forceinline__ void attn_tile(
    const u16* Kl, const u16* Vl, u16* Plw, int k0, int qrow, int lq, int lg,
    bf16x8 qf0, bf16x8 qf1, float& m_run, float& l_run, f32x4* accO, bool masked) {
  f32x4 zero4 = {0.f, 0.f, 0.f, 0.f};
  f32x4 sa[4];
  sa[0] = zero4; sa[1] = zero4; sa[2] = zero4; sa[3] = zero4;
  __builtin_amdgcn_s_setprio(1);
#pragma unroll
  for (int kt = 0; kt < 4; ++kt) {
    int krow = kt * 16 + lq;
    int base = krow * 128 + lg * 16;
    int swz = (krow & 7) << 4;
    bf16x8 kf0 = *(const bf16x8*)((const char*)Kl + (base ^ swz));
    bf16x8 kf1 = *(const bf16x8*)((const char*)Kl + ((base + 64) ^ swz));
    sa[kt] = mfma16(kf0, qf0, sa[kt]);
    sa[kt] = mfma16(kf1, qf1, sa[kt]);
  }
  __builtin_amdgcn_s_setprio(0);

  float p[16];
#pragma unroll
  for (int kt = 0; kt < 4; ++kt)
#pragma unroll
    for (int r = 0; r < 4; ++r) p[kt * 4 + r] = sa[kt][r];
  if (masked) {
#pragma unroll
    for (int kt = 0; kt < 4; ++kt)
#pragma unroll
      for (int r = 0; r < 4; ++r) {
        int key = k0 + kt * 16 + lg * 4 + r;
        if (key > qrow) p[kt * 4 + r] = -1e30f;
      }
  }
  // depth-4 pairwise max tree
  float x0 = fmaxf(p[0], p[1]), x1 = fmaxf(p[2], p[3]);
  float x2 = fmaxf(p[4], p[5]), x3 = fmaxf(p[6], p[7]);
  float x4 = fmaxf(p[8], p[9]), x5 = fmaxf(p[10], p[11]);
  float x6 = fmaxf(p[12], p[13]), x7 = fmaxf(p[14], p[15]);
  x0 = fmaxf(x0, x1); x2 = fmaxf(x2, x3); x4 = fmaxf(x4, x5); x6 = fmaxf(x6, x7);
  x0 = fmaxf(x0, x2); x4 = fmaxf(x4, x6);
  float pm = fmaxf(x0, x4);
  pm = fmaxf(pm, __shfl_xor(pm, 16));
  pm = xor32_max(pm);
  const bool resc = __any(pm > m_run + 8.0f);  // defer-max, wave-uniform
  float mnew = resc ? fmaxf(m_run, pm) : m_run;
#pragma unroll
  for (int i = 0; i < 16; ++i) p[i] = __builtin_amdgcn_exp2f(p[i] - mnew);
  // depth-4 pairwise sum tree
  float s0 = p[0] + p[1], s1 = p[2] + p[3], s2 = p[4] + p[5], s3 = p[6] + p[7];
  float s4 = p[8] + p[9], s5 = p[10] + p[11], s6 = p[12] + p[13], s7 = p[14] + p[15];
  s0 += s1; s2 += s3; s4 += s5; s6 += s7;
  s0 += s2; s4 += s6;
  float rs = s0 + s4;
  rs += __shfl_xor(rs, 16);
  rs = xor32_add(rs);
  if (resc) {
    float alpha = __builtin_amdgcn_exp2f(m_run - mnew);
    l_run = l_run * alpha + rs;
    m_run = mnew;
#pragma unroll
    for (int r = 0; r < 4; ++r) {
      float ar = __shfl(alpha, lg * 4 + r);
#pragma unroll
      for (int dt = 0; dt < 4; ++dt) accO[dt][r] *= ar;
    }
  } else {
    l_run += rs;
  }

  // P -> per-wave LDS (bf16 via v_cvt_pk, swizzled [q][k])
  {
    int swz = (lq & 7) << 4;
#pragma unroll
    for (int kt = 0; kt < 4; ++kt) {
      u32 w0, w1;
      asm("v_cvt_pk_bf16_f32 %0, %1, %2"
          : "=v"(w0) : "v"(p[kt * 4 + 0]), "v"(p[kt * 4 + 1]));
      asm("v_cvt_pk_bf16_f32 %0, %1, %2"
          : "=v"(w1) : "v"(p[kt * 4 + 2]), "v"(p[kt * 4 + 3]));
      int a0 = (lq * 128 + (kt * 16 + lg * 4) * 2) ^ swz;
      int a1 = (lq * 128 + (kt * 16 + lg * 4 + 2) * 2) ^ swz;
      *(u32*)((char*)Plw + a0) = w0;
      *(u32*)((char*)Plw + a1) = w1;
    }
  }
  // PV: O[q][d] += P[q][k] * V[k][d]
  {
    int swz = (lq & 7) << 4;
    bf16x8 pa0 = *(const bf16x8*)((const char*)Plw + ((lq * 128 + lg * 16) ^ swz));
    bf16x8 pa1 = *(const bf16x8*)((const char*)Plw + ((lq * 128 + 64 + lg * 16) ^ swz));
    __builtin_amdgcn_s_setprio(1);
#pragma unroll
    for (int dt = 0; dt < 4; ++dt) {
      int vrow = dt * 16 + lq;
      int vb = vrow * 128 + lg * 16;
      int vs = (vrow & 7) << 4;
      bf16x8 v0 = *(const bf16x8*)((const char*)Vl + (vb ^ vs));
      bf16x8 v1 = *(const bf16x8*)((const char*)Vl + ((vb + 64) ^ vs));
      accO[dt] = mfma16(pa0, v0, accO[dt]);
      accO[dt] = mfma16(pa1, v1, accO[dt]);
    }
    __builtin_amdgcn_s_setprio(0);
  }
}

// ---------------- causal flash attention ----------------
// 1024 flat blocks of 4 waves, KVBLK=64 dbuf (40KB LDS) -> ALL blocks
// co-resident at 4 blocks/CU = 4 waves/SIMD. Each block: ONE 64-row q-block
// (qb), all 4 waves do exactly qb+1 subtiles. Flat-id -> (qb,bh) mapping puts
// qbs {j, 15-j, 16+j, 31-j} (sum 62) on the 4 blocks a CU receives under
// round-robin dispatch -> per-CU work uniform (perf heuristic only).
__global__ __launch_bounds__(256, 4) void k_attn(const u16* __restrict__ qh,
                                                 const u16* __restrict__ kh,
                                                 const u16* __restrict__ vt,
                                                 u16* __restrict__ ao) {
  const int id = (int)blockIdx.x;  // 0..1023
  const int g = id & 255;
  const int s_ = id >> 8;          // co-residency slot 0..3
  const int bh = g >> 3;
  const int j = g & 7;
  const int qb = s_ == 0 ? j : (s_ == 1 ? 15 - j : (s_ == 2 ? 16 + j : 31 - j));
  const int tid = threadIdx.x;
  const int w = tid >> 6;  // 0..3
  const int lane = tid & 63;
  const int lq = lane & 15;
  const int lg = lane >> 4;

  __shared__ __align__(16) u16 Kd[2][64 * 64];  // 16 KB
  __shared__ __align__(16) u16 Vd[2][64 * 64];  // 16 KB
  __shared__ __align__(16) u16 Pl[4][16 * 64];  // 8 KB

  const int qtop = qb * 64 + w * 16;
  const int qrow = qtop + lq;

  const u16* qp = qh + ((size_t)bh * SEQ + qrow) * DK + lg * 8;
  bf16x8 qf0 = *(const bf16x8*)qp;
  bf16x8 qf1 = *(const bf16x8*)(qp + 32);

  f32x4 zero4 = {0.f, 0.f, 0.f, 0.f};
  f32x4 acc[4];
#pragma unroll
  for (int dt = 0; dt < 4; ++dt) acc[dt] = zero4;
  float m_run = -1e30f, l_run = 0.f;

  const int NT = qb + 1;  // uniform for all 4 waves of this block

  const char* kb_ = (const char*)kh + (size_t)bh * SEQ * 128;  // 128 B/row
  const char* vb_ = (const char*)vt + (size_t)bh * DK * 4096;  // 4096 B/row

  // prologue: stage subtile 0 into buf 0 (2 chunks of 16B per thread)
#pragma unroll
  for (int pass = 0; pass < 2; ++pass) {
    int chunk = pass * 256 + tid;          // 0..511
    int srow = chunk >> 3;                 // 0..63
    int colb = ((chunk & 7) * 16) ^ ((srow & 7) << 4);
    gload16(kb_ + (size_t)srow * 128 + colb, (char*)Kd[0] + chunk * 16);
    gload16(vb_ + (size_t)srow * 4096 + colb, (char*)Vd[0] + chunk * 16);
  }
  __syncthreads();

  for (int t = 0; t < NT; ++t) {
    const int cur = t & 1;
    if (t + 1 < NT) {  // stage next subtile; lands during compute
      int kb0 = (t + 1) * 64;
#pragma unroll
      for (int pass = 0; pass < 2; ++pass) {
        int chunk = pass * 256 + tid;
        int srow = chunk >> 3;
        int colb = ((chunk & 7) * 16) ^ ((srow & 7) << 4);
        gload16(kb_ + (size_t)(kb0 + srow) * 128 + colb,
                (char*)Kd[cur ^ 1] + chunk * 16);
        gload16(vb_ + (size_t)srow * 4096 + kb0 * 2 + colb,
                (char*)Vd[cur ^ 1] + chunk * 16);
      }
    }
    attn_tile(Kd[cur], Vd[cur], Pl[w], t * 64, qrow, lq, lg, qf0, qf1,
              m_run, l_run, acc, t == NT - 1);
    __syncthreads();  // one barrier per 64 keys (drains next-subtile DMA)
  }

  const int b = bh >> 4, h = bh & 15;
#pragma unroll
  for (int r = 0; r < 4; ++r) {
    float lr = __shfl(l_run, lg * 4 + r);
    float inv = 1.f / (lr + 1e-9f);
    int qq = qtop + lg * 4 + r;
    u16* orow = ao + ((size_t)b * SEQ + qq) * D_MODEL + h * DK;
#pragma unroll
    for (int dt = 0; dt < 4; ++dt) orow[dt * 16 + lq] = f2bf(acc[dt][r] * inv);
  }
}

extern "C" void kernel_launch(void* const* d_in, const int* in_sizes, int n_in,
                              void* d_out, int out_size, void* d_ws, size_t ws_size,
                              hipStream_t stream) {
  const float* x = (const float*)d_in[0];
  const float* wq = (const float*)d_in[1];
  const float* wk = (const float*)d_in[2];
  const float* wv = (const float*)d_in[3];
  const float* wo = (const float*)d_in[4];
  float* out = (float*)d_out;
  char* ws = (char*)d_ws;

  u16* xb   = (u16*)(ws + 0);             // 8 MB
  u16* wqb  = (u16*)(ws + 8388608);       // 2 MB each
  u16* wkb  = (u16*)(ws + 10485760);
  u16* wvb  = (u16*)(ws + 12582912);
  u16* wob  = (u16*)(ws + 14680064);
  u16* qkv  = (u16*)(ws + 16777216);      // 24 MB [4096][3072]
  u16* qhb  = (u16*)(ws + 41943040);      // 8 MB [32][2048][64]
  u16* khb  = (u16*)(ws + 50331648);      // 8 MB
  u16* vtb  = (u16*)(ws + 58720256);      // 8 MB [32][64][2048]
  u16* aob  = (u16*)(ws + 67108864);      // 8 MB [4096][1024]
  float* ct = (float*)(ws + 75497472);    // 256 KB
  float* st = (float*)(ws + 75759616);    // 256 KB

  k_cast<<<4352, 256, 0, stream>>>(x, wq, wk, wv, wo, xb, wqb, wkb, wvb, wob, ct, st);
  k_gemm3<<<dim3(32, 24), 256, 0, stream>>>(xb, wqb, wkb, wvb, qkv);
  k_rope<<<dim3(2048, 2), 256, 0, stream>>>(qkv, ct, st, qhb, khb);
  k_vtrans<<<dim3(32, 32), 256, 0, stream>>>(qkv, vtb);
  k_attn<<<1024, 256, 0, stream>>>(qhb, khb, vtb, aob);
  k_gemmo<<<dim3(32, 16), 256, 0, stream>>>(aob, wob, out);
}

// Round 18
// 112.948 us; speedup vs baseline: 1.0085x; 1.0019x over previous
//
#include <hip/hip_runtime.h>
#include <stdint.h>

typedef unsigned short u16;
typedef unsigned int u32;
typedef __bf16 bf16x8 __attribute__((ext_vector_type(8)));
typedef float f32x4 __attribute__((ext_vector_type(4)));
typedef unsigned short u16x8 __attribute__((ext_vector_type(8)));

#define D_MODEL 1024
#define SEQ 2048
#define NH 16
#define DK 64
#define NROWS 4096  // B*S

static __device__ __forceinline__ u16 f2bf(float f) {
  u32 u = __float_as_uint(f);
  u = (u + 0x7FFFu + ((u >> 16) & 1u)) >> 16;
  return (u16)u;
}
static __device__ __forceinline__ float bf2f(u16 h) {
  return __uint_as_float(((u32)h) << 16);
}
static __device__ __forceinline__ f32x4 mfma16(bf16x8 a, bf16x8 b, f32x4 c) {
  return __builtin_amdgcn_mfma_f32_16x16x32_bf16(a, b, c, 0, 0, 0);
}
static __device__ __forceinline__ void gload16(const void* g, void* l) {
  __builtin_amdgcn_global_load_lds(
      (const __attribute__((address_space(1))) void*)g,
      (__attribute__((address_space(3))) void*)l, 16, 0, 0);
}

// lane i gets op(x[i], x[i^32]) in ALL lanes, via v_permlane32_swap (VALU pipe).
static __device__ __forceinline__ float xor32_max(float x) {
#if __has_builtin(__builtin_amdgcn_permlane32_swap)
  u32 a = __float_as_uint(x), b = a;
  auto pr = __builtin_amdgcn_permlane32_swap(a, b, false, false);
  return fmaxf(__uint_as_float(pr[0]), __uint_as_float(pr[1]));
#else
  return fmaxf(x, __shfl_xor(x, 32));
#endif
}
static __device__ __forceinline__ float xor32_add(float x) {
#if __has_builtin(__builtin_amdgcn_permlane32_swap)
  u32 a = __float_as_uint(x), b = a;
  auto pr = __builtin_amdgcn_permlane32_swap(a, b, false, false);
  return __uint_as_float(pr[0]) + __uint_as_float(pr[1]);
#else
  return x + __shfl_xor(x, 32);
#endif
}

// ---------------- fp32 -> bf16 cast of x + weights; tail blocks build RoPE tables ----------------
__global__ __launch_bounds__(256) void k_cast(
    const float* __restrict__ x, const float* __restrict__ wq,
    const float* __restrict__ wk, const float* __restrict__ wv,
    const float* __restrict__ wo, u16* __restrict__ xb, u16* __restrict__ wqb,
    u16* __restrict__ wkb, u16* __restrict__ wvb, u16* __restrict__ wob,
    float* __restrict__ ct, float* __restrict__ st) {
  if (blockIdx.x >= 4096) {  // RoPE tables: 65536 (s,p) entries, fp64 on device
    int i = (int)(blockIdx.x - 4096) * 256 + threadIdx.x;
    int s = i >> 5, p = i & 31;
    double ang = (double)s * pow(10000.0, -(double)p / 32.0);
    ct[i] = (float)cos(ang);
    st[i] = (float)sin(ang);
    return;
  }
  size_t e = ((size_t)blockIdx.x * 256 + threadIdx.x) * 8;
  const float* s;
  u16* d;
  size_t off;
  if (e < (size_t)NROWS * D_MODEL) {
    s = x; d = xb; off = e;
  } else {
    size_t r = e - (size_t)NROWS * D_MODEL;
    unsigned wi = (unsigned)(r >> 20);
    off = r & 1048575u;
    s = wi == 0 ? wq : wi == 1 ? wk : wi == 2 ? wv : wo;
    d = wi == 0 ? wqb : wi == 1 ? wkb : wi == 2 ? wvb : wob;
  }
  float4 a = *(const float4*)(s + off);
  float4 b = *(const float4*)(s + off + 4);
  u16x8 o;
  o[0] = f2bf(a.x); o[1] = f2bf(a.y); o[2] = f2bf(a.z); o[3] = f2bf(a.w);
  o[4] = f2bf(b.x); o[5] = f2bf(b.y); o[6] = f2bf(b.z); o[7] = f2bf(b.w);
  *(u16x8*)(d + off) = o;
}

// ---------------- fused QKV bf16 B^T GEMM: qkv[4096][3072] ----------------
// m97 structure, BK=64 (32 MFMA per barrier-pair) + T2 XOR-swizzled LDS:
// linear DMA dest + inverse-swizzled global source col + swizzled ds_read.
__global__ __launch_bounds__(256, 1) void k_gemm3(
    const u16* __restrict__ A, const u16* __restrict__ B0,
    const u16* __restrict__ B1, const u16* __restrict__ B2,
    u16* __restrict__ Cb) {
  constexpr int K = 1024;
  const int mb = blockIdx.x, nb = blockIdx.y;
  const int tid = threadIdx.x;
  const int lane = tid & 63, w = tid >> 6;
  const int lq = lane & 15, lg = lane >> 4;
  const int wm = w >> 1, wn = w & 1;
  __shared__ __align__(16) u16 As[128 * 64];  // 16 KB, row = 128 B
  __shared__ __align__(16) u16 Bs[128 * 64];  // 16 KB

  const int sel = nb >> 3;
  const u16* Bp = sel == 0 ? B0 : (sel == 1 ? B1 : B2);
  const int nloc = (nb & 7) * 128;
  const char* Ab = (const char*)A + (size_t)mb * 128 * 2048;
  const char* Bb = (const char*)Bp + (size_t)nloc * 2048;

  f32x4 zero4 = {0.f, 0.f, 0.f, 0.f};
  f32x4 acc[4][4];
#pragma unroll
  for (int i = 0; i < 4; ++i)
#pragma unroll
    for (int j = 0; j < 4; ++j) acc[i][j] = zero4;

  for (int k0 = 0; k0 < K; k0 += 64) {
#pragma unroll
    for (int c = 0; c < 4; ++c) {
      int ch = c * 256 + tid;                         // 0..1023 16B chunks
      int srow = ch >> 3;                             // 0..127
      int scb = ((ch & 7) * 16) ^ ((srow & 7) << 4);  // inverse-swizzled source
      const char* ga = Ab + (size_t)srow * 2048 + k0 * 2 + scb;
      const char* gb = Bb + (size_t)srow * 2048 + k0 * 2 + scb;
      gload16(ga, (char*)As + ch * 16);               // linear dest
      gload16(gb, (char*)Bs + ch * 16);
    }
    __syncthreads();  // drains DMA + aligns waves
#pragma unroll
    for (int ks = 0; ks < 2; ++ks) {
      bf16x8 af[4], bfr[4];
#pragma unroll
      for (int i = 0; i < 4; ++i) {
        int ra = wm * 64 + i * 16 + lq;
        int rb = wn * 64 + i * 16 + lq;
        af[i] = *(const bf16x8*)((const char*)As +
                                 ra * 128 + ((ks * 64 + lg * 16) ^ ((ra & 7) << 4)));
        bfr[i] = *(const bf16x8*)((const char*)Bs +
                                  rb * 128 + ((ks * 64 + lg * 16) ^ ((rb & 7) << 4)));
      }
#pragma unroll
      for (int i = 0; i < 4; ++i)
#pragma unroll
        for (int j = 0; j < 4; ++j) acc[i][j] = mfma16(af[i], bfr[j], acc[i][j]);
    }
    __syncthreads();  // reads done before next-tile DMA overwrites
  }

#pragma unroll
  for (int i = 0; i < 4; ++i) {
#pragma unroll
    for (int r = 0; r < 4; ++r) {
      size_t rowg = (size_t)(mb * 128 + wm * 64 + i * 16 + lg * 4 + r);
#pragma unroll
      for (int j = 0; j < 4; ++j) {
        int colg = nb * 128 + wn * 64 + j * 16 + lq;
        Cb[rowg * 3072 + colg] = f2bf(acc[i][j][r]);
      }
    }
  }
}

// ---------------- RoPE apply + reshape to head-major [BH][S][64] ----------------
// Q additionally pre-scaled by 0.125*log2(e) (exp2-domain softmax downstream).
__global__ __launch_bounds__(256) void k_rope(const u16* __restrict__ qkv,
                                              const float* __restrict__ ct,
                                              const float* __restrict__ st,
                                              u16* __restrict__ qh, u16* __restrict__ kh) {
  int gi = blockIdx.x * 256 + threadIdx.x;  // 524288
  int row = gi >> 7;
  int col = (gi & 127) << 3;
  int h = col >> 6, d0 = col & 63;
  int b = row >> 11, s = row & 2047;
  const int srcoff = blockIdx.y ? 1024 : 0;
  const float qs = blockIdx.y ? 1.0f : 0.18033688011112042f;
  u16x8 v = *(const u16x8*)(qkv + (size_t)row * 3072 + srcoff + col);
  const float* cp = ct + s * 32 + (d0 >> 1);
  const float* sp = st + s * 32 + (d0 >> 1);
  u16x8 o;
#pragma unroll
  for (int i = 0; i < 4; ++i) {
    float ev = bf2f(v[2 * i]), od = bf2f(v[2 * i + 1]);
    float c = cp[i], sn = sp[i];
    o[2 * i] = f2bf((ev * c - od * sn) * qs);
    o[2 * i + 1] = f2bf((ev * sn + od * c) * qs);
  }
  u16* dst = blockIdx.y ? kh : qh;
  *(u16x8*)(dst + (((size_t)(b * 16 + h) * SEQ + s) << 6) + d0) = o;
}

// ---------------- V transpose: qkv V cols -> Vt [BH][64][S] ----------------
__global__ __launch_bounds__(256) void k_vtrans(const u16* __restrict__ qkv,
                                                u16* __restrict__ vt) {
  __shared__ __align__(16) u16 t[64][72];
  int sb = blockIdx.x, bh = blockIdx.y;
  int b = bh >> 4, h = bh & 15;
  int tid = threadIdx.x;
#pragma unroll
  for (int c = 0; c < 2; ++c) {
    int o = tid * 8 + c * 2048;
    int r = o >> 6, d = o & 63;
    u16x8 v = *(const u16x8*)(qkv + (size_t)(b * SEQ + sb * 64 + r) * 3072 + 2048 + h * 64 + d);
    *(u16x8*)&t[r][d] = v;
  }
  __syncthreads();
#pragma unroll
  for (int c = 0; c < 2; ++c) {
    int o = tid * 8 + c * 2048;
    int d = o >> 6, si = o & 63;
    u16x8 v;
#pragma unroll
    for (int j = 0; j < 8; ++j) v[j] = t[si + j][d];
    *(u16x8*)(vt + ((size_t)bh * 64 + d) * SEQ + sb * 64 + si) = v;
  }
}

// ---------------- out-projection GEMM: BM=128 BN=64, BK=64, swizzled ----------------
__global__ __launch_bounds__(256, 2) void k_gemmo(const u16* __restrict__ A,
                                                  const u16* __restrict__ B0,
                                                  float* __restrict__ Cf) {
  constexpr int K = 1024;
  const int mb = blockIdx.x, nb = blockIdx.y;
  const int tid = threadIdx.x;
  const int lane = tid & 63, w = tid >> 6;
  const int lq = lane & 15, lg = lane >> 4;
  const int wm = w >> 1, wn = w & 1;
  __shared__ __align__(16) u16 As[128 * 64];  // 16 KB
  __shared__ __align__(16) u16 Bs[64 * 64];   // 8 KB

  const char* Ab = (const char*)A + (size_t)mb * 128 * 2048;
  const char* Bb = (const char*)B0 + (size_t)(nb * 64) * 2048;

  f32x4 zero4 = {0.f, 0.f, 0.f, 0.f};
  f32x4 acc[4][2];
#pragma unroll
  for (int i = 0; i < 4; ++i) {
    acc[i][0] = zero4; acc[i][1] = zero4;
  }

  for (int k0 = 0; k0 < K; k0 += 64) {
#pragma unroll
    for (int c = 0; c < 4; ++c) {
      int ch = c * 256 + tid;
      int srow = ch >> 3;
      int scb = ((ch & 7) * 16) ^ ((srow & 7) << 4);
      gload16(Ab + (size_t)srow * 2048 + k0 * 2 + scb, (char*)As + ch * 16);
      if (c < 2)
        gload16(Bb + (size_t)srow * 2048 + k0 * 2 + scb, (char*)Bs + ch * 16);
    }
    __syncthreads();
#pragma unroll
    for (int ks = 0; ks < 2; ++ks) {
      bf16x8 af[4], bfr[2];
#pragma unroll
      for (int i = 0; i < 4; ++i) {
        int ra = wm * 64 + i * 16 + lq;
        af[i] = *(const bf16x8*)((const char*)As +
                                 ra * 128 + ((ks * 64 + lg * 16) ^ ((ra & 7) << 4)));
      }
#pragma unroll
      for (int j = 0; j < 2; ++j) {
        int rb = wn * 32 + j * 16 + lq;
        bfr[j] = *(const bf16x8*)((const char*)Bs +
                                  rb * 128 + ((ks * 64 + lg * 16) ^ ((rb & 7) << 4)));
      }
#pragma unroll
      for (int i = 0; i < 4; ++i)
#pragma unroll
        for (int j = 0; j < 2; ++j) acc[i][j] = mfma16(af[i], bfr[j], acc[i][j]);
    }
    __syncthreads();
  }

#pragma unroll
  for (int i = 0; i < 4; ++i) {
#pragma unroll
    for (int r = 0; r < 4; ++r) {
      size_t rowg = (size_t)(mb * 128 + wm * 64 + i * 16 + lg * 4 + r);
#pragma unroll
      for (int j = 0; j < 2; ++j) {
        int colg = nb * 64 + wn * 32 + j * 16 + lq;
        Cf[rowg * 1024 + colg] = acc[i][j][r];
      }
    }
  }
}

// ---------------- one kv-subtile (64 keys) for one 16-row strip ----------------
static __device__ __forceinline__ void attn_tile(
    const u16* Kl, const u16* Vl, u16* Plw, int k0, int qrow, int lq, int lg,
    bf16x8 qf0, bf16x8 qf1, float& m_run, float& l_run, f32x4* accO, bool masked) {
  f32x4 zero4 = {0.f, 0.f, 0.f, 0.f};
  f32x4 sa[4];
  sa[0] = zero4; sa[1] = zero4; sa[2] = zero4; sa[3] = zero4;
  __builtin_amdgcn_s_setprio(1);
#pragma unroll
  for (int kt = 0; kt < 4; ++kt) {
    int krow = kt * 16 + lq;
    int base = krow * 128 + lg * 16;
    int swz = (krow & 7) << 4;
    bf16x8 kf0 = *(const bf16x8*)((const char*)Kl + (base ^ swz));
    bf16x8 kf1 = *(const bf16x8*)((const char*)Kl + ((base + 64) ^ swz));
    sa[kt] = mfma16(kf0, qf0, sa[kt]);
    sa[kt] = mfma16(kf1, qf1, sa[kt]);
  }
  __builtin_amdgcn_s_setprio(0);

  float p[16];
#pragma unroll
  for (int kt = 0; kt < 4; ++kt)
#pragma unroll
    for (int r = 0; r < 4; ++r) p[kt * 4 + r] = sa[kt][r];
  if (masked) {
#pragma unroll
    for (int kt = 0; kt < 4; ++kt)
#pragma unroll
      for (int r = 0; r < 4; ++r) {
        int key = k0 + kt * 16 + lg * 4 + r;
        if (key > qrow) p[kt * 4 + r] = -1e30f;
      }
  }
  // depth-4 pairwise max tree
  float x0 = fmaxf(p[0], p[1]), x1 = fmaxf(p[2], p[3]);
  float x2 = fmaxf(p[4], p[5]), x3 = fmaxf(p[6], p[7]);
  float x4 = fmaxf(p[8], p[9]), x5 = fmaxf(p[10], p[11]);
  float x6 = fmaxf(p[12], p[13]), x7 = fmaxf(p[14], p[15]);
  x0 = fmaxf(x0, x1); x2 = fmaxf(x2, x3); x4 = fmaxf(x4, x5); x6 = fmaxf(x6, x7);
  x0 = fmaxf(x0, x2); x4 = fmaxf(x4, x6);
  float pm = fmaxf(x0, x4);
  pm = fmaxf(pm, __shfl_xor(pm, 16));
  pm = xor32_max(pm);
  const bool resc = __any(pm > m_run + 8.0f);  // defer-max, wave-uniform
  float mnew = resc ? fmaxf(m_run, pm) : m_run;
#pragma unroll
  for (int i = 0; i < 16; ++i) p[i] = __builtin_amdgcn_exp2f(p[i] - mnew);
  // depth-4 pairwise sum tree
  float s0 = p[0] + p[1], s1 = p[2] + p[3], s2 = p[4] + p[5], s3 = p[6] + p[7];
  float s4 = p[8] + p[9], s5 = p[10] + p[11], s6 = p[12] + p[13], s7 = p[14] + p[15];
  s0 += s1; s2 += s3; s4 += s5; s6 += s7;
  s0 += s2; s4 += s6;
  float rs = s0 + s4;
  rs += __shfl_xor(rs, 16);
  rs = xor32_add(rs);
  if (resc) {
    float alpha = __builtin_amdgcn_exp2f(m_run - mnew);
    l_run = l_run * alpha + rs;
    m_run = mnew;
#pragma unroll
    for (int r = 0; r < 4; ++r) {
      float ar = __shfl(alpha, lg * 4 + r);
#pragma unroll
      for (int dt = 0; dt < 4; ++dt) accO[dt][r] *= ar;
    }
  } else {
    l_run += rs;
  }

  // P -> per-wave LDS (bf16 via v_cvt_pk, swizzled [q][k])
  {
    int swz = (lq & 7) << 4;
#pragma unroll
    for (int kt = 0; kt < 4; ++kt) {
      u32 w0, w1;
      asm("v_cvt_pk_bf16_f32 %0, %1, %2"
          : "=v"(w0) : "v"(p[kt * 4 + 0]), "v"(p[kt * 4 + 1]));
      asm("v_cvt_pk_bf16_f32 %0, %1, %2"
          : "=v"(w1) : "v"(p[kt * 4 + 2]), "v"(p[kt * 4 + 3]));
      int a0 = (lq * 128 + (kt * 16 + lg * 4) * 2) ^ swz;
      int a1 = (lq * 128 + (kt * 16 + lg * 4 + 2) * 2) ^ swz;
      *(u32*)((char*)Plw + a0) = w0;
      *(u32*)((char*)Plw + a1) = w1;
    }
  }
  // PV: O[q][d] += P[q][k] * V[k][d]
  {
    int swz = (lq & 7) << 4;
    bf16x8 pa0 = *(const bf16x8*)((const char*)Plw + ((lq * 128 + lg * 16) ^ swz));
    bf16x8 pa1 = *(const bf16x8*)((const char*)Plw + ((lq * 128 + 64 + lg * 16) ^ swz));
    __builtin_amdgcn_s_setprio(1);
#pragma unroll
    for (int dt = 0; dt < 4; ++dt) {
      int vrow = dt * 16 + lq;
      int vb = vrow * 128 + lg * 16;
      int vs = (vrow & 7) << 4;
      bf16x8 v0 = *(const bf16x8*)((const char*)Vl + (vb ^ vs));
      bf16x8 v1 = *(const bf16x8*)((const char*)Vl + ((vb + 64) ^ vs));
      accO[dt] = mfma16(pa0, v0, accO[dt]);
      accO[dt] = mfma16(pa1, v1, accO[dt]);
    }
    __builtin_amdgcn_s_setprio(0);
  }
}

// ---------------- causal flash attention ----------------
// grid (16 pairs, 32 bh) = 512 blocks of 4 waves -> 2 independent blocks/CU.
// Block handles 64-row q-blocks qb1=x and qb2=31-x; per-wave work uniform.
// KVBLK=128 staged per iteration as two 64-key subtiles (double-buffered
// global_load_lds, linear dest + inverse-swizzled source); ONE barrier per
// 128 keys.
__global__ __launch_bounds__(256, 2) void k_attn(const u16* __restrict__ qh,
                                                 const u16* __restrict__ kh,
                                                 const u16* __restrict__ vt,
                                                 u16* __restrict__ ao) {
  const int qb1 = (int)blockIdx.x;   // 0..15
  const int qb2 = 31 - qb1;          // 16..31
  const int bh = blockIdx.y;
  const int tid = threadIdx.x;
  const int w = tid >> 6;  // 0..3
  const int lane = tid & 63;
  const int lq = lane & 15;
  const int lg = lane >> 4;

  __shared__ __align__(16) u16 Kd[2][2][64 * 64];
  __shared__ __align__(16) u16 Vd[2][2][64 * 64];
  __shared__ __align__(16) u16 Pl[4][16 * 64];

  const int qtop1 = qb1 * 64 + w * 16;
  const int qtop2 = qb2 * 64 + w * 16;
  const int qrow1 = qtop1 + lq;
  const int qrow2 = qtop2 + lq;

  const u16* qp1 = qh + ((size_t)bh * SEQ + qrow1) * DK + lg * 8;
  const u16* qp2 = qh + ((size_t)bh * SEQ + qrow2) * DK + lg * 8;
  bf16x8 qa0 = *(const bf16x8*)qp1;
  bf16x8 qa1 = *(const bf16x8*)(qp1 + 32);
  bf16x8 qc0 = *(const bf16x8*)qp2;
  bf16x8 qc1 = *(const bf16x8*)(qp2 + 32);

  f32x4 zero4 = {0.f, 0.f, 0.f, 0.f};
  f32x4 acc1[4], acc2[4];
#pragma unroll
  for (int dt = 0; dt < 4; ++dt) { acc1[dt] = zero4; acc2[dt] = zero4; }
  float m1 = -1e30f, l1 = 0.f, m2 = -1e30f, l2 = 0.f;

  const int nt1 = qb1 + 1;           // strip subtile participation
  const int nt2 = qb2 + 1;
  const int NIT = (nt2 + 1) >> 1;    // 128-key iterations

  const char* kb_ = (const char*)kh + (size_t)bh * SEQ * 128;  // 128 B/row
  const char* vb_ = (const char*)vt + (size_t)bh * DK * 4096;  // 4096 B/row

  // prologue: stage tile 0 (subtiles 0,1) into buf 0
#pragma unroll
  for (int s = 0; s < 2; ++s)
#pragma unroll
    for (int pass = 0; pass < 2; ++pass) {
      int chunk = pass * 256 + tid;          // 0..511
      int srow = chunk >> 3;                 // 0..63
      int colb = ((chunk & 7) * 16) ^ ((srow & 7) << 4);
      gload16(kb_ + (size_t)(s * 64 + srow) * 128 + colb,
              (char*)Kd[0][s] + chunk * 16);
      gload16(vb_ + (size_t)srow * 4096 + (s * 64) * 2 + colb,
              (char*)Vd[0][s] + chunk * 16);
    }
  __syncthreads();

  for (int it = 0; it < NIT; ++it) {
    const int cur = it & 1;
    if (it + 1 < NIT) {  // stage next 128-key tile; lands during compute
      int kb0 = (it + 1) * 128;
#pragma unroll
      for (int s = 0; s < 2; ++s)
#pragma unroll
        for (int pass = 0; pass < 2; ++pass) {
          int chunk = pass * 256 + tid;
          int srow = chunk >> 3;
          int colb = ((chunk & 7) * 16) ^ ((srow & 7) << 4);
          gload16(kb_ + (size_t)(kb0 + s * 64 + srow) * 128 + colb,
                  (char*)Kd[cur ^ 1][s] + chunk * 16);
          gload16(vb_ + (size_t)srow * 4096 + (kb0 + s * 64) * 2 + colb,
                  (char*)Vd[cur ^ 1][s] + chunk * 16);
        }
    }
#pragma unroll
    for (int s = 0; s < 2; ++s) {
      const int tsub = it * 2 + s;
      const int k0 = tsub * 64;
      if (tsub < nt1)
        attn_tile(Kd[cur][s], Vd[cur][s], Pl[w], k0, qrow1, lq, lg, qa0, qa1,
                  m1, l1, acc1, tsub == nt1 - 1);
      if (tsub < nt2)
        attn_tile(Kd[cur][s], Vd[cur][s], Pl[w], k0, qrow2, lq, lg, qc0, qc1,
                  m2, l2, acc2, tsub == nt2 - 1);
    }
    __syncthreads();  // one barrier per 128 keys (drains next-tile DMA)
  }

  const int b = bh >> 4, h = bh & 15;
#pragma unroll
  for (int r = 0; r < 4; ++r) {
    float lr = __shfl(l1, lg * 4 + r);
    float inv = 1.f / (lr + 1e-9f);
    int qq = qtop1 + lg * 4 + r;
    u16* orow = ao + ((size_t)b * SEQ + qq) * D_MODEL + h * DK;
#pragma unroll
    for (int dt = 0; dt < 4; ++dt) orow[dt * 16 + lq] = f2bf(acc1[dt][r] * inv);
  }
#pragma unroll
  for (int r = 0; r < 4; ++r) {
    float lr = __shfl(l2, lg * 4 + r);
    float inv = 1.f / (lr + 1e-9f);
    int qq = qtop2 + lg * 4 + r;
    u16* orow = ao + ((size_t)b * SEQ + qq) * D_MODEL + h * DK;
#pragma unroll
    for (int dt = 0; dt < 4; ++dt) orow[dt * 16 + lq] = f2bf(acc2[dt][r] * inv);
  }
}

extern "C" void kernel_launch(void* const* d_in, const int* in_sizes, int n_in,
                              void* d_out, int out_size, void* d_ws, size_t ws_size,
                              hipStream_t stream) {
  const float* x = (const float*)d_in[0];
  const float* wq = (const float*)d_in[1];
  const float* wk = (const float*)d_in[2];
  const float* wv = (const float*)d_in[3];
  const float* wo = (const float*)d_in[4];
  float* out = (float*)d_out;
  char* ws = (char*)d_ws;

  u16* xb   = (u16*)(ws + 0);             // 8 MB
  u16* wqb  = (u16*)(ws + 8388608);       // 2 MB each
  u16* wkb  = (u16*)(ws + 10485760);
  u16* wvb  = (u16*)(ws + 12582912);
  u16* wob  = (u16*)(ws + 14680064);
  u16* qkv  = (u16*)(ws + 16777216);      // 24 MB [4096][3072]
  u16* qhb  = (u16*)(ws + 41943040);      // 8 MB [32][2048][64]
  u16* khb  = (u16*)(ws + 50331648);      // 8 MB
  u16* vtb  = (u16*)(ws + 58720256);      // 8 MB [32][64][2048]
  u16* aob  = (u16*)(ws + 67108864);      // 8 MB [4096][1024]
  float* ct = (float*)(ws + 75497472);    // 256 KB
  float* st = (float*)(ws + 75759616);    // 256 KB

  k_cast<<<4352, 256, 0, stream>>>(x, wq, wk, wv, wo, xb, wqb, wkb, wvb, wob, ct, st);
  k_gemm3<<<dim3(32, 24), 256, 0, stream>>>(xb, wqb, wkb, wvb, qkv);
  k_rope<<<dim3(2048, 2), 256, 0, stream>>>(qkv, ct, st, qhb, khb);
  k_vtrans<<<dim3(32, 32), 256, 0, stream>>>(qkv, vtb);
  k_attn<<<dim3(16, 32), 256, 0, stream>>>(qhb, khb, vtb, aob);
  k_gemmo<<<dim3(32, 16), 256, 0, stream>>>(aob, wob, out);
}